// Round 6
// baseline (270.322 us; speedup 1.0000x reference)
//
#include <hip/hip_runtime.h>
#include <math.h>

typedef __attribute__((ext_vector_type(8))) short short8;
typedef __attribute__((ext_vector_type(4))) float float4v;
typedef unsigned int uint;

#define BATCH 8
#define SEQ   4096
#define DIM   768
#define HID   512
#define M_TOK (BATCH * SEQ)   // 32768

// ---------- helpers ----------
static __device__ __forceinline__ short f2bf_rne(float x) {
    unsigned int u = __float_as_uint(x);
    unsigned int r = (u + 0x7FFFu + ((u >> 16) & 1u)) >> 16;   // RNE
    return (short)r;
}
// pack two floats -> 2 bf16 (truncate) in ONE v_perm_b32. lo=bf16(a), hi=bf16(b).
static __device__ __forceinline__ uint pack_bf2(float a, float b) {
    return __builtin_amdgcn_perm(__float_as_uint(b), __float_as_uint(a), 0x07060302u);
}
union FragU { uint u[4]; short8 s; };
// async global->LDS DMA, 16 B per lane; lds dest = uniform base + lane*16,
// global src is PER-LANE (this is how we pre-apply the layout permutation).
static __device__ __forceinline__ void gl2lds16(const void* g, void* l) {
    __builtin_amdgcn_global_load_lds(
        (const __attribute__((address_space(1))) unsigned int*)g,
        (__attribute__((address_space(3))) unsigned int*)l, 16, 0, 0);
}

// ---------- prep: LDS-tiled transpose W1 [DIM][HID] fp32 -> W1T [HID][DIM] bf16 ----------
__global__ __launch_bounds__(256) void prep_kernel(const float* __restrict__ W1,
                                                   short* __restrict__ W1T) {
    __shared__ float t[64][65];
    const int bk = blockIdx.x % 12, bn = blockIdx.x / 12;   // 12 k-tiles x 8 n-tiles
    const int k0 = bk * 64, n0 = bn * 64;
    const int tr = threadIdx.x >> 6, tc = threadIdx.x & 63;
#pragma unroll
    for (int i = 0; i < 16; i++) {
        int k = tr + i * 4;
        t[k][tc] = W1[(size_t)(k0 + k) * HID + n0 + tc];
    }
    __syncthreads();
#pragma unroll
    for (int i = 0; i < 16; i++) {
        int n = tr + i * 4;
        W1T[(size_t)(n0 + n) * DIM + k0 + tc] = f2bf_rne(t[tc][n]);
    }
}

// ---------- MLP: m97-clone geometry. Block = 128M x 128N, BK=32, 24 steps.
// 4 waves (2x2, each 64x64, acc[4][4]). SINGLE-buffered 24 KB LDS, plain
// 2-barrier loop. Grid 1024 -> 4 blocks/CU = 16 DMA-issuing waves/CU (the
// variable all prior rounds held at 8; delivery scales ~1.2 B/cyc/wave).
// N-split is legal: logits = sum_n relu(h)*W2[n] decomposes over n-slices;
// block writes part[bn][m], boundary_kernel sums the 4 partials.
// XCD-chunked swizzle: the 4 n-siblings of an A-tile land on one XCD (L2 reuse).
// LDS panels in FRAGMENT ORDER: every ds_read_b128 is base + lane*16 (linear,
// conflict-free); the permutation is pre-applied to the per-lane global addresses.
#define MLP_BM    128
#define MLP_BN    128
#define MLP_STEPS 24
#define MLP_ABYTES 16384            // 128 rows x 32 k x 4 B (fp32 A)
#define MLP_BBYTES 8192             // 128 n x 32 k x 2 B (bf16 B)
#define MLP_LDS   (MLP_ABYTES + MLP_BBYTES)   // 24576 -> 4+ blocks/CU

__global__ __launch_bounds__(256, 4) void mlp_kernel(const float* __restrict__ A,
                                                     const short* __restrict__ BT,
                                                     const float* __restrict__ b1,
                                                     const float* __restrict__ W2,
                                                     float* __restrict__ part) {
    __shared__ char smem[MLP_LDS];
    const int tid = threadIdx.x, wave = tid >> 6, lane = tid & 63;
    const int q = lane >> 4, r = lane & 15;
    const int wr = wave >> 1, wc = wave & 1;     // 2x2 wave grid, 64x64 each

    // bijective XCD-chunked swizzle (1024 % 8 == 0): XCD x gets works x*128..x*128+127,
    // i.e. 32 consecutive m-tiles with all 4 n-slices -> A-panel L2 reuse within XCD.
    const int bid = blockIdx.x;
    const int work = (bid & 7) * 128 + (bid >> 3);
    const int mt = work >> 2, bn = work & 3;
    const int m0 = mt * MLP_BM, n0 = bn * MLP_BN;

    // ---- DMA descriptors (per-lane global src, wave-uniform LDS dest) ----
    // A: 16 instrs of 1 KB; instr i: row-group g=i>>1 (16 rows), chunk c=i&1.
    // lane l=q*16+r fetches row (m0+g*16+r), floats k = q*8+c*4 ..+3;
    // HW writes LDS at base(g*2048+c*1024) + l*16  (linear fragment order).
    const float* aSrc[4];
    int aDst[4];
#pragma unroll
    for (int j = 0; j < 4; j++) {
        int i = wave * 4 + j, g = i >> 1, c = i & 1;
        aSrc[j] = A + (size_t)(m0 + g * 16 + r) * DIM + q * 8 + c * 4;
        aDst[j] = g * 2048 + c * 1024;
    }
    // B: 8 instrs of 1 KB; instr h: n-group (16 rows). lane l fetches row
    // (n0+h*16+r), shorts k=q*8..+7 -> LDS base ABYTES + h*1024 (+ l*16 by HW).
    const short* bSrc[2];
    int bDst[2];
#pragma unroll
    for (int j = 0; j < 2; j++) {
        int h = wave * 2 + j;
        bSrc[j] = BT + (size_t)(n0 + h * 16 + r) * DIM + q * 8;
        bDst[j] = MLP_ABYTES + h * 1024;
    }

    float4v acc[4][4] = {};

    for (int p = 0; p < MLP_STEPS; ++p) {
        const int ko = p * 32;
#pragma unroll
        for (int j = 0; j < 4; j++) gl2lds16(aSrc[j] + ko, smem + aDst[j]);
#pragma unroll
        for (int j = 0; j < 2; j++) gl2lds16(bSrc[j] + ko, smem + bDst[j]);
        __syncthreads();   // DMA drained (vmcnt0 in barrier) + all waves arrived

        short8 bfr[4];
#pragma unroll
        for (int nf = 0; nf < 4; nf++)
            bfr[nf] = *(const short8*)(smem + MLP_ABYTES + (wc * 4 + nf) * 1024 + lane * 16);
#pragma unroll
        for (int mf = 0; mf < 4; mf++) {
            const int g = wr * 4 + mf;
            float4v f0 = *(const float4v*)(smem + g * 2048 + lane * 16);          // k=q*8+0..3
            float4v f1 = *(const float4v*)(smem + g * 2048 + 1024 + lane * 16);   // k=q*8+4..7
            FragU af;
            af.u[0] = pack_bf2(f0[0], f0[1]);
            af.u[1] = pack_bf2(f0[2], f0[3]);
            af.u[2] = pack_bf2(f1[0], f1[1]);
            af.u[3] = pack_bf2(f1[2], f1[3]);
#pragma unroll
            for (int nf = 0; nf < 4; nf++)
                acc[mf][nf] = __builtin_amdgcn_mfma_f32_16x16x32_bf16(
                    af.s, bfr[nf], acc[mf][nf], 0, 0, 0);
        }
        __syncthreads();   // all frag reads done before next DMA overwrite
    }

    // epilogue: h = relu(acc + b1); partial W2-dot over this wave's 64 cols
    float b1v[4], w2v[4];
#pragma unroll
    for (int nf = 0; nf < 4; nf++) {
        int gc = n0 + wc * 64 + nf * 16 + r;
        b1v[nf] = b1[gc];
        w2v[nf] = W2[gc];
    }
    float* red = (float*)smem;   // [2 col-halves][128 rows] fp32 = 1 KB
#pragma unroll
    for (int mf = 0; mf < 4; mf++)
#pragma unroll
        for (int v = 0; v < 4; v++) {
            float pp = 0.f;
#pragma unroll
            for (int nf = 0; nf < 4; nf++) {
                float hh = acc[mf][nf][v] + b1v[nf];
                hh = hh > 0.f ? hh : 0.f;
                pp += hh * w2v[nf];
            }
#pragma unroll
            for (int off = 1; off < 16; off <<= 1) pp += __shfl_xor(pp, off, 64);
            if (r == 0) red[wc * 128 + wr * 64 + mf * 16 + q * 4 + v] = pp;
        }
    __syncthreads();
    if (tid < 128) {
        part[(size_t)bn * M_TOK + m0 + tid] = red[tid] + red[128 + tid];
    }
}

// ---------- boundary: partial logits -> hard bits, per-batch scan -> segment starts ----------
__global__ __launch_bounds__(1024) void boundary_kernel(const float* __restrict__ part,
                                                        const float* __restrict__ b2p,
                                                        const float* __restrict__ noise,
                                                        int* __restrict__ starts,   // [BATCH][SEQ+1]
                                                        int* __restrict__ nseg,     // [BATCH]
                                                        int* __restrict__ nbcount) {// [BATCH]
    const int b = blockIdx.x, tid = threadIdx.x;
    const int base = tid * 4;
    const float b2 = b2p[0];
    int h[4], c = 0;
#pragma unroll
    for (int j = 0; j < 4; j++) {
        int l = base + j;
        int g = b * SEQ + l;
        float u = noise[g];
        float lg = part[g] + part[M_TOK + g] + part[2 * M_TOK + g] + part[3 * M_TOK + g]
                 + b2 + logf(u) - log1pf(-u);
        h[j] = (lg > 0.f) ? 1 : 0;
        c += h[j];
    }
    const int lane = tid & 63, wid = tid >> 6;
    int inc = c;
    for (int off = 1; off < 64; off <<= 1) {
        int t = __shfl_up(inc, off, 64);
        if (lane >= off) inc += t;
    }
    __shared__ int wtot[16], woff[16], extra[2];
    if (lane == 63) wtot[wid] = inc;
    if (tid == 1023) extra[0] = h[3];
    __syncthreads();
    if (tid == 0) {
        int s = 0;
        for (int i = 0; i < 16; i++) { woff[i] = s; s += wtot[i]; }
        extra[1] = s;
    }
    __syncthreads();
    int run = (inc - c) + woff[wid];       // exclusive prefix of hard bits
#pragma unroll
    for (int j = 0; j < 4; j++) {
        int l = base + j;
        if (h[j]) {
            run++;
            if (l < SEQ - 1) starts[b * (SEQ + 1) + run] = l + 1;
        }
    }
    if (tid == 0) {
        int total = extra[1];
        int ns = total + (extra[0] ? 0 : 1);
        starts[b * (SEQ + 1)] = 0;
        starts[b * (SEQ + 1) + ns] = SEQ;
        nseg[b] = ns;
        nbcount[b] = total;
    }
}

// ---------- pool: 4 waves/block, one wave per slot; 2-way row unroll; NT stores ----------
__global__ __launch_bounds__(256) void pool_kernel(const float* __restrict__ hidden,
                                                   const int* __restrict__ starts,
                                                   const int* __restrict__ nseg,
                                                   float* __restrict__ out) {
    const int wid = threadIdx.x >> 6, lane = threadIdx.x & 63;
    const int s = blockIdx.x * 4 + wid, b = blockIdx.y;
    float* orow = out + (size_t)(b * SEQ + s) * DIM;
    float4v a0 = {0.f, 0.f, 0.f, 0.f}, a1 = a0, a2 = a0;
    const int ns = nseg[b];
    if (s < ns) {
        const int st = starts[b * (SEQ + 1) + s];
        const int en = starts[b * (SEQ + 1) + s + 1];
        float4v c0 = a0, c1 = a0, c2 = a0;
        const float* hbase = hidden + (size_t)(b * SEQ) * DIM;
        int row = st;
        for (; row + 2 <= en; row += 2) {
            const float* h0 = hbase + (size_t)row * DIM;
            const float* h1 = h0 + DIM;
            a0 += *(const float4v*)(h0 + lane * 4);
            a1 += *(const float4v*)(h0 + (lane + 64) * 4);
            a2 += *(const float4v*)(h0 + (lane + 128) * 4);
            c0 += *(const float4v*)(h1 + lane * 4);
            c1 += *(const float4v*)(h1 + (lane + 64) * 4);
            c2 += *(const float4v*)(h1 + (lane + 128) * 4);
        }
        if (row < en) {
            const float* h0 = hbase + (size_t)row * DIM;
            a0 += *(const float4v*)(h0 + lane * 4);
            a1 += *(const float4v*)(h0 + (lane + 64) * 4);
            a2 += *(const float4v*)(h0 + (lane + 128) * 4);
        }
        a0 += c0; a1 += c1; a2 += c2;
        const float invc = 1.f / (float)(en - st);
        a0 *= invc; a1 *= invc; a2 *= invc;
    }
    __builtin_nontemporal_store(a0, (float4v*)(orow + lane * 4));
    __builtin_nontemporal_store(a1, (float4v*)(orow + (lane + 64) * 4));
    __builtin_nontemporal_store(a2, (float4v*)(orow + (lane + 128) * 4));
}

// ---------- finalize: loss / num_boundaries / total_positions ----------
__global__ void finalize_kernel(const int* __restrict__ nbcount, float* __restrict__ tail) {
    int nb = 0;
    for (int i = 0; i < BATCH; i++) nb += nbcount[i];
    float ratio = (float)nb / (float)M_TOK;
    float d = fabsf(ratio - 0.25f) - 0.05f;    // PRIOR + 0.05 = 0.25, margin 0.05
    tail[0] = d > 0.f ? d : 0.f;
    tail[1] = (float)nb;
    tail[2] = (float)M_TOK;
}

// ---------- launch ----------
extern "C" void kernel_launch(void* const* d_in, const int* in_sizes, int n_in,
                              void* d_out, int out_size, void* d_ws, size_t ws_size,
                              hipStream_t stream) {
    const float* hidden = (const float*)d_in[0];
    const float* W1     = (const float*)d_in[1];
    const float* b1     = (const float*)d_in[2];
    const float* W2     = (const float*)d_in[3];
    const float* b2     = (const float*)d_in[4];
    const float* noise  = (const float*)d_in[5];

    char* ws = (char*)d_ws;
    short* W1T    = (short*)(ws);                       // 786432 B
    float* part   = (float*)(ws + 786432);              // 4 x 32768 x 4 = 524288 B
    int*   starts = (int*)(ws + 786432 + 524288);       // 131104 B
    int*   nseg   = (int*)(ws + 786432 + 524288 + 131104);  // 32 B
    int*   nbcount = nseg + 8;                          // 32 B
    float* out    = (float*)d_out;

    prep_kernel<<<96, 256, 0, stream>>>(W1, W1T);
    mlp_kernel<<<(M_TOK / MLP_BM) * (HID / MLP_BN), 256, 0, stream>>>(hidden, W1T, b1, W2, part);
    boundary_kernel<<<BATCH, 1024, 0, stream>>>(part, b2, noise, starts, nseg, nbcount);
    pool_kernel<<<dim3(SEQ / 4, BATCH), 256, 0, stream>>>(hidden, starts, nseg, out);
    finalize_kernel<<<1, 1, 0, stream>>>(nbcount, out + (size_t)M_TOK * DIM);
}

// Round 7
// 225.281 us; speedup vs baseline: 1.1999x; 1.1999x over previous
//
#include <hip/hip_runtime.h>
#include <math.h>

typedef __attribute__((ext_vector_type(8))) short short8;
typedef __attribute__((ext_vector_type(4))) float float4v;
typedef unsigned int uint;

#define BATCH 8
#define SEQ   4096
#define DIM   768
#define HID   512
#define M_TOK (BATCH * SEQ)   // 32768

// ---------- helpers ----------
static __device__ __forceinline__ short f2bf_rne(float x) {
    unsigned int u = __float_as_uint(x);
    unsigned int r = (u + 0x7FFFu + ((u >> 16) & 1u)) >> 16;   // RNE
    return (short)r;
}
// pack two floats -> 2 bf16 (truncate) in ONE v_perm_b32. lo=bf16(a), hi=bf16(b).
static __device__ __forceinline__ uint pack_bf2(float a, float b) {
    return __builtin_amdgcn_perm(__float_as_uint(b), __float_as_uint(a), 0x07060302u);
}
union FragU { uint u[4]; short8 s; };
// async global->LDS DMA, 16 B per lane; lds dest = uniform base + lane*16,
// global src is PER-LANE.
static __device__ __forceinline__ void gl2lds16(const void* g, void* l) {
    __builtin_amdgcn_global_load_lds(
        (const __attribute__((address_space(1))) unsigned int*)g,
        (__attribute__((address_space(3))) unsigned int*)l, 16, 0, 0);
}

// ---------- prep: LDS-tiled transpose W1 [DIM][HID] fp32 -> W1T [HID][DIM] bf16 ----------
__global__ __launch_bounds__(256) void prep_kernel(const float* __restrict__ W1,
                                                   short* __restrict__ W1T) {
    __shared__ float t[64][65];
    const int bk = blockIdx.x % 12, bn = blockIdx.x / 12;   // 12 k-tiles x 8 n-tiles
    const int k0 = bk * 64, n0 = bn * 64;
    const int tr = threadIdx.x >> 6, tc = threadIdx.x & 63;
#pragma unroll
    for (int i = 0; i < 16; i++) {
        int k = tr + i * 4;
        t[k][tc] = W1[(size_t)(k0 + k) * HID + n0 + tc];
    }
    __syncthreads();
#pragma unroll
    for (int i = 0; i < 16; i++) {
        int n = tr + i * 4;
        W1T[(size_t)(n0 + n) * DIM + k0 + tc] = f2bf_rne(t[tc][n]);
    }
}

// ---------- MLP: block = 128M x 512N (full N), 8 waves (2M x 4N, 64x128 each).
// BK=64, 12 steps. ROOT-CAUSE FIX (R0-R6 all staged at ~10 B/cyc/CU): DMA source
// segments were 64 B scattered rows; BK=64 makes every DMA instruction read full
// cache lines (A: 4 rows x 256 B; B: 8 rows x 128 B) -> m97-class ~20+ B/cyc/CU.
// LDS is row-major (A [128][64]f32 rows=256B, B [512][64]bf16 rows=128B) with an
// XOR chunk-swizzle (rule #21: same involution pre-applied to per-lane global src
// AND to ds_read addr; permutes 16B chunks WITHIN a row -> contiguity preserved,
// bank-conflict-free frag reads). A double-buffered (2x32KB) + B single (64KB) =
// 128 KB. Counted vmcnt(4): A 2-iter lead, B 1-barrier lead; drain only at tail.
__global__ __launch_bounds__(512, 2) void mlp_kernel(const float* __restrict__ A,
                                                     const short* __restrict__ BT,
                                                     const float* __restrict__ b1,
                                                     const float* __restrict__ W2,
                                                     float* __restrict__ logits) {
    extern __shared__ char smem[];
    const int tid = threadIdx.x, wave = tid >> 6, lane = tid & 63;
    const int q = lane >> 4, r = lane & 15;
    const int wr = wave >> 2, wc = wave & 3;     // 2x4 wave grid
    const int m0 = blockIdx.x * 128;
    const int s7 = r & 7;

    char* rng0 = smem;                 // A ring buf 0: [128 rows][64 f32] = 32 KB
    char* rng1 = smem + 32768;         // A ring buf 1
    char* Bb   = smem + 65536;         // B panel: [512 n][64 bf16] = 64 KB

    // ---- DMA descriptors. A: 32 instrs of 1KB (4 rows x 256B); wave w -> i=w*4+j.
    // lane l: row = i*4 + (l>>4); LDS chunk kc_lds = l&15 holds global chunk
    // kc_glob = kc_lds ^ (row&7)  (XOR involution; dest = i*1024 + l*16 linear).
    const float* aSrc[4];
    int aD[4];
#pragma unroll
    for (int j = 0; j < 4; j++) {
        int i = wave * 4 + j;
        int row = i * 4 + (lane >> 4);
        int kc = (lane & 15) ^ (row & 7);
        aSrc[j] = A + (size_t)(m0 + row) * DIM + kc * 4;
        aD[j] = i * 1024;
    }
    // B: 64 instrs of 1KB (8 rows x 128B); wave w -> i=w*8+j. lane l: n = i*8+(l>>3);
    // LDS chunk c_lds = l&7 holds global chunk c_glob = c_lds ^ (n&7).
    const short* bSrc[8];
    int bD[8];
#pragma unroll
    for (int j = 0; j < 8; j++) {
        int i = wave * 8 + j;
        int n = i * 8 + (lane >> 3);
        int c = (lane & 7) ^ (n & 7);
        bSrc[j] = BT + (size_t)n * DIM + c * 8;
        bD[j] = i * 1024;
    }

    // ---- frag-read offsets (swizzled; row&7 == r&7 for all our rows) ----
    // A: row = wr*64 + mf*16 + r; chunk kc = kk*8 + q*2 + c -> byte row*256 + (kc^s7)*16
    int aOff[2][2];
#pragma unroll
    for (int kk = 0; kk < 2; kk++)
#pragma unroll
        for (int c = 0; c < 2; c++)
            aOff[kk][c] = (wr * 64 + r) * 256 + (((kk * 8 + q * 2 + c) ^ s7) * 16);
    // B: n = wc*128 + nf*16 + r; chunk = kk*4 + q -> byte n*128 + (chunk^s7)*16
    int bOff[2];
#pragma unroll
    for (int kk = 0; kk < 2; kk++)
        bOff[kk] = (wc * 128 + r) * 128 + (((kk * 4 + q) ^ s7) * 16);

    float4v acc[4][8] = {};

    auto stageA = [&](int t, char* rb) {        // 4 DMA instrs / wave
        const int ko = t * 64;                  // float offset
#pragma unroll
        for (int j = 0; j < 4; j++) gl2lds16(aSrc[j] + ko, rb + aD[j]);
    };
    auto stageB = [&](int t) {                  // 8 DMA instrs / wave
        const int ko = t * 64;                  // short offset
#pragma unroll
        for (int j = 0; j < 8; j++) gl2lds16(bSrc[j] + ko, Bb + bD[j]);
    };
    auto compute = [&](const char* ab) {        // 64 MFMA / wave / step
#pragma unroll
        for (int kk = 0; kk < 2; kk++) {
            short8 bfr[8];
#pragma unroll
            for (int nf = 0; nf < 8; nf++)
                bfr[nf] = *(const short8*)(Bb + bOff[kk] + nf * 2048);
#pragma unroll
            for (int mf = 0; mf < 4; mf++) {
                float4v f0 = *(const float4v*)(ab + aOff[kk][0] + mf * 4096);
                float4v f1 = *(const float4v*)(ab + aOff[kk][1] + mf * 4096);
                FragU af;
                af.u[0] = pack_bf2(f0[0], f0[1]);
                af.u[1] = pack_bf2(f0[2], f0[3]);
                af.u[2] = pack_bf2(f1[0], f1[1]);
                af.u[3] = pack_bf2(f1[2], f1[3]);
#pragma unroll
                for (int nf = 0; nf < 8; nf++)
                    acc[mf][nf] = __builtin_amdgcn_mfma_f32_16x16x32_bf16(
                        af.s, bfr[nf], acc[mf][nf], 0, 0, 0);
            }
        }
    };

    // prologue: B(0) oldest, then A(0), A(1) -> 16 outstanding / wave
    stageB(0);
    stageA(0, rng0);
    stageA(1, rng1);

    // iters 0..10: wait A(t)+B(t) (allowed newest = A(t+2):4 -> vmcnt(4));
    // after read-done barrier: stage B(t+1) (before A so A stays newest), A(t+2).
    for (int t = 0; t < 11; ++t) {
        asm volatile("s_waitcnt vmcnt(4)" ::: "memory");
        __builtin_amdgcn_s_barrier();
        __builtin_amdgcn_sched_barrier(0);
        compute((t & 1) ? rng1 : rng0);
        __builtin_amdgcn_sched_barrier(0);
        __builtin_amdgcn_s_barrier();           // all reads of A-buf and Bb done
        stageB(t + 1);
        if (t <= 9) stageA(t + 2, (t & 1) ? rng1 : rng0);
    }
    // iter 11: everything must land
    asm volatile("s_waitcnt vmcnt(0)" ::: "memory");
    __builtin_amdgcn_s_barrier();
    __builtin_amdgcn_sched_barrier(0);
    compute(rng1);
    __syncthreads();

    // epilogue (R2-proven): h = relu(acc + b1); partial over this wave's 128 cols
    float b1v[8], w2v[8];
#pragma unroll
    for (int nf = 0; nf < 8; nf++) {
        int gc = wc * 128 + nf * 16 + r;
        b1v[nf] = b1[gc];
        w2v[nf] = W2[gc];
    }
    float* red = (float*)smem;   // [4 colgroups][128 rows] fp32 = 2 KB
#pragma unroll
    for (int mf = 0; mf < 4; mf++)
#pragma unroll
        for (int v = 0; v < 4; v++) {
            float pp = 0.f;
#pragma unroll
            for (int nf = 0; nf < 8; nf++) {
                float hh = acc[mf][nf][v] + b1v[nf];
                hh = hh > 0.f ? hh : 0.f;
                pp += hh * w2v[nf];
            }
#pragma unroll
            for (int off = 1; off < 16; off <<= 1) pp += __shfl_xor(pp, off, 64);
            if (r == 0) red[wc * 128 + wr * 64 + mf * 16 + q * 4 + v] = pp;
        }
    __syncthreads();
    if (tid < 128) {
        logits[m0 + tid] = red[tid] + red[128 + tid] + red[256 + tid] + red[384 + tid];
    }
}

// ---------- boundary: logits -> hard bits, per-batch scan -> segment starts ----------
__global__ __launch_bounds__(1024) void boundary_kernel(const float* __restrict__ logits,
                                                        const float* __restrict__ b2p,
                                                        const float* __restrict__ noise,
                                                        int* __restrict__ starts,   // [BATCH][SEQ+1]
                                                        int* __restrict__ nseg,     // [BATCH]
                                                        int* __restrict__ nbcount) {// [BATCH]
    const int b = blockIdx.x, tid = threadIdx.x;
    const int base = tid * 4;
    const float b2 = b2p[0];
    int h[4], c = 0;
#pragma unroll
    for (int j = 0; j < 4; j++) {
        int l = base + j;
        float u = noise[b * SEQ + l];
        float lg = logits[b * SEQ + l] + b2 + logf(u) - log1pf(-u);
        h[j] = (lg > 0.f) ? 1 : 0;
        c += h[j];
    }
    const int lane = tid & 63, wid = tid >> 6;
    int inc = c;
    for (int off = 1; off < 64; off <<= 1) {
        int t = __shfl_up(inc, off, 64);
        if (lane >= off) inc += t;
    }
    __shared__ int wtot[16], woff[16], extra[2];
    if (lane == 63) wtot[wid] = inc;
    if (tid == 1023) extra[0] = h[3];
    __syncthreads();
    if (tid == 0) {
        int s = 0;
        for (int i = 0; i < 16; i++) { woff[i] = s; s += wtot[i]; }
        extra[1] = s;
    }
    __syncthreads();
    int run = (inc - c) + woff[wid];       // exclusive prefix of hard bits
#pragma unroll
    for (int j = 0; j < 4; j++) {
        int l = base + j;
        if (h[j]) {
            run++;
            if (l < SEQ - 1) starts[b * (SEQ + 1) + run] = l + 1;
        }
    }
    if (tid == 0) {
        int total = extra[1];
        int ns = total + (extra[0] ? 0 : 1);
        starts[b * (SEQ + 1)] = 0;
        starts[b * (SEQ + 1) + ns] = SEQ;
        nseg[b] = ns;
        nbcount[b] = total;
    }
}

// ---------- pool: 4 waves/block, one wave per slot; 2-way row unroll; NT stores ----------
__global__ __launch_bounds__(256) void pool_kernel(const float* __restrict__ hidden,
                                                   const int* __restrict__ starts,
                                                   const int* __restrict__ nseg,
                                                   float* __restrict__ out) {
    const int wid = threadIdx.x >> 6, lane = threadIdx.x & 63;
    const int s = blockIdx.x * 4 + wid, b = blockIdx.y;
    float* orow = out + (size_t)(b * SEQ + s) * DIM;
    float4v a0 = {0.f, 0.f, 0.f, 0.f}, a1 = a0, a2 = a0;
    const int ns = nseg[b];
    if (s < ns) {
        const int st = starts[b * (SEQ + 1) + s];
        const int en = starts[b * (SEQ + 1) + s + 1];
        float4v c0 = a0, c1 = a0, c2 = a0;
        const float* hbase = hidden + (size_t)(b * SEQ) * DIM;
        int row = st;
        for (; row + 2 <= en; row += 2) {
            const float* h0 = hbase + (size_t)row * DIM;
            const float* h1 = h0 + DIM;
            a0 += *(const float4v*)(h0 + lane * 4);
            a1 += *(const float4v*)(h0 + (lane + 64) * 4);
            a2 += *(const float4v*)(h0 + (lane + 128) * 4);
            c0 += *(const float4v*)(h1 + lane * 4);
            c1 += *(const float4v*)(h1 + (lane + 64) * 4);
            c2 += *(const float4v*)(h1 + (lane + 128) * 4);
        }
        if (row < en) {
            const float* h0 = hbase + (size_t)row * DIM;
            a0 += *(const float4v*)(h0 + lane * 4);
            a1 += *(const float4v*)(h0 + (lane + 64) * 4);
            a2 += *(const float4v*)(h0 + (lane + 128) * 4);
        }
        a0 += c0; a1 += c1; a2 += c2;
        const float invc = 1.f / (float)(en - st);
        a0 *= invc; a1 *= invc; a2 *= invc;
    }
    __builtin_nontemporal_store(a0, (float4v*)(orow + lane * 4));
    __builtin_nontemporal_store(a1, (float4v*)(orow + (lane + 64) * 4));
    __builtin_nontemporal_store(a2, (float4v*)(orow + (lane + 128) * 4));
}

// ---------- finalize: loss / num_boundaries / total_positions ----------
__global__ void finalize_kernel(const int* __restrict__ nbcount, float* __restrict__ tail) {
    int nb = 0;
    for (int i = 0; i < BATCH; i++) nb += nbcount[i];
    float ratio = (float)nb / (float)M_TOK;
    float d = fabsf(ratio - 0.25f) - 0.05f;    // PRIOR + 0.05 = 0.25, margin 0.05
    tail[0] = d > 0.f ? d : 0.f;
    tail[1] = (float)nb;
    tail[2] = (float)M_TOK;
}

// ---------- launch ----------
#define MLP_LDS 131072
extern "C" void kernel_launch(void* const* d_in, const int* in_sizes, int n_in,
                              void* d_out, int out_size, void* d_ws, size_t ws_size,
                              hipStream_t stream) {
    const float* hidden = (const float*)d_in[0];
    const float* W1     = (const float*)d_in[1];
    const float* b1     = (const float*)d_in[2];
    const float* W2     = (const float*)d_in[3];
    const float* b2     = (const float*)d_in[4];
    const float* noise  = (const float*)d_in[5];

    char* ws = (char*)d_ws;
    short* W1T    = (short*)(ws);                    // 786432 B
    float* logits = (float*)(ws + 786432);           // 131072 B
    int*   starts = (int*)(ws + 917504);             // 131104 B
    int*   nseg   = (int*)(ws + 917504 + 131104);    // 32 B
    int*   nbcount = nseg + 8;                       // 32 B
    float* out    = (float*)d_out;

    static bool s_mlp_attr = false;
    if (!s_mlp_attr) {
        hipFuncSetAttribute(reinterpret_cast<const void*>(mlp_kernel),
                            hipFuncAttributeMaxDynamicSharedMemorySize, MLP_LDS);
        s_mlp_attr = true;
    }

    prep_kernel<<<96, 256, 0, stream>>>(W1, W1T);
    mlp_kernel<<<M_TOK / 128, 512, MLP_LDS, stream>>>(hidden, W1T, b1, W2, logits);
    boundary_kernel<<<BATCH, 1024, 0, stream>>>(logits, b2, noise, starts, nseg, nbcount);
    pool_kernel<<<dim3(SEQ / 4, BATCH), 256, 0, stream>>>(hidden, starts, nseg, out);
    finalize_kernel<<<1, 1, 0, stream>>>(nbcount, out + (size_t)M_TOK * DIM);
}